// Round 1
// baseline (87.369 us; speedup 1.0000x reference)
//
#include <hip/hip_runtime.h>
#include <hip/hip_bf16.h>

typedef short bf16x8 __attribute__((ext_vector_type(8)));
typedef float f32x4  __attribute__((ext_vector_type(4)));
typedef unsigned short u16;

// float -> bf16 with round-to-nearest-even
static __device__ __forceinline__ u16 f2bf(float f) {
    unsigned u = __float_as_uint(f);
    u += 0x7FFFu + ((u >> 16) & 1u);
    return (u16)(u >> 16);
}
static __device__ __forceinline__ float bf2f(u16 b) {
    return __uint_as_float(((unsigned)b) << 16);
}

// ---------------------------------------------------------------------------
// Kernel 1: W' [256 cols][128 k] bf16, transposed so B-fragments are 16B
// contiguous. W'[c][k] = W1[k][c] for c<128 (P half), W1[128+k][c-128] (Q).
// ---------------------------------------------------------------------------
__global__ void prep_w(const float* __restrict__ W1, u16* __restrict__ Wl) {
    int idx = blockIdx.x * 256 + threadIdx.x;   // over W1 flat [256][128]
    if (idx >= 256 * 128) return;
    int r = idx >> 7;     // W1 row 0..255
    int q = idx & 127;    // W1 col 0..127
    int k = (r < 128) ? r : (r - 128);
    int c = (r < 128) ? q : (q + 128);
    Wl[c * 128 + k] = f2bf(W1[idx]);
}

// ---------------------------------------------------------------------------
// Kernel 2: PQ[m][0:256] = z[m][0:128] @ W'  (bf16 MFMA, fp32 accum)
// BM=128 rows/block, 4 waves each own a 64-wide N slice, K=128 in one shot.
// A tile in LDS, XOR-swizzled (row-major 256B rows -> 32-way conflict else).
// ---------------------------------------------------------------------------
#define BM 128
__global__ __launch_bounds__(256, 1) void node_gemm(
    const float* __restrict__ z,   // [M][128] fp32
    const u16*   __restrict__ Wl,  // [256][128] bf16
    u16*         __restrict__ PQ,  // [M][256] bf16
    int M)
{
    __shared__ char As[BM * 256];  // BM rows x 128 bf16 (256 B/row), swizzled
    const int tid  = threadIdx.x;
    const int lane = tid & 63;
    const int wave = tid >> 6;
    const int m0   = blockIdx.x * BM;

    // ---- stage A: fp32 -> bf16, swizzled write. 16 float4 chunks/thread ----
    #pragma unroll
    for (int i = 0; i < (BM * 32) / 256; ++i) {
        int ci  = tid + i * 256;        // chunk id: 32 float4-chunks per row
        int row = ci >> 5;
        int c4  = ci & 31;
        float4 v = make_float4(0.f, 0.f, 0.f, 0.f);
        if (m0 + row < M)
            v = *(const float4*)(z + (size_t)(m0 + row) * 128 + c4 * 4);
        ushort4 b;
        b.x = f2bf(v.x); b.y = f2bf(v.y); b.z = f2bf(v.z); b.w = f2bf(v.w);
        int byte = row * 256 + ((c4 * 8) ^ ((row & 7) << 4));
        *(ushort4*)(As + byte) = b;
    }
    __syncthreads();

    f32x4 acc[8][4];
    #pragma unroll
    for (int mi = 0; mi < 8; ++mi)
        #pragma unroll
        for (int nf = 0; nf < 4; ++nf)
            acc[mi][nf] = (f32x4){0.f, 0.f, 0.f, 0.f};

    const int g  = lane >> 4;     // k-group 0..3
    const int ln = lane & 15;     // m (A) / n (B) lane
    const int n0 = wave * 64;

    #pragma unroll
    for (int ks = 0; ks < 4; ++ks) {
        bf16x8 b[4];
        #pragma unroll
        for (int nf = 0; nf < 4; ++nf) {
            int c = n0 + nf * 16 + ln;
            b[nf] = *(const bf16x8*)(Wl + c * 128 + ks * 32 + g * 8);
        }
        #pragma unroll
        for (int mi = 0; mi < 8; ++mi) {
            int row  = mi * 16 + ln;
            int byte = row * 256 + ((ks * 64 + g * 16) ^ ((row & 7) << 4));
            bf16x8 a = *(const bf16x8*)(As + byte);
            #pragma unroll
            for (int nf = 0; nf < 4; ++nf)
                acc[mi][nf] = __builtin_amdgcn_mfma_f32_16x16x32_bf16(
                    a, b[nf], acc[mi][nf], 0, 0, 0);
        }
    }

    // ---- C write: col = lane&15, row = (lane>>4)*4 + reg  (verified layout)
    #pragma unroll
    for (int mi = 0; mi < 8; ++mi) {
        #pragma unroll
        for (int nf = 0; nf < 4; ++nf) {
            #pragma unroll
            for (int r = 0; r < 4; ++r) {
                int row = m0 + mi * 16 + g * 4 + r;
                if (row < M) {
                    int col = n0 + nf * 16 + ln;
                    PQ[(size_t)row * 256 + col] = f2bf(acc[mi][nf][r]);
                }
            }
        }
    }
}

// ---------------------------------------------------------------------------
// Kernel 3: out[e] = relu(P[s] + Q[d] + b1) . W2 + b2.  16 lanes per edge,
// each lane covers 8 of the 128 hidden units (one 16B bf16 load per operand).
// ---------------------------------------------------------------------------
__global__ __launch_bounds__(256) void edge_mlp(
    const int* __restrict__ ei,    // [2][E] int32
    const u16* __restrict__ PQ,    // [M][256] bf16
    const float* __restrict__ b1,  // [128]
    const float* __restrict__ W2,  // [128]
    const float* __restrict__ b2,  // [1]
    float* __restrict__ out,       // [E]
    int E)
{
    int gid = blockIdx.x * 256 + threadIdx.x;
    int e   = gid >> 4;
    if (e >= E) return;
    int sub = gid & 15;

    int s = ei[e];
    int d = ei[E + e];

    uint4 pv = *(const uint4*)(PQ + (size_t)s * 256 + sub * 8);
    uint4 qv = *(const uint4*)(PQ + (size_t)d * 256 + 128 + sub * 8);
    float4 b1a = *(const float4*)(b1 + sub * 8);
    float4 b1b = *(const float4*)(b1 + sub * 8 + 4);
    float4 w2a = *(const float4*)(W2 + sub * 8);
    float4 w2b = *(const float4*)(W2 + sub * 8 + 4);

    const u16* pu = (const u16*)&pv;
    const u16* qu = (const u16*)&qv;
    float bb[8] = {b1a.x, b1a.y, b1a.z, b1a.w, b1b.x, b1b.y, b1b.z, b1b.w};
    float ww[8] = {w2a.x, w2a.y, w2a.z, w2a.w, w2b.x, w2b.y, w2b.z, w2b.w};

    float acc = 0.f;
    #pragma unroll
    for (int j = 0; j < 8; ++j) {
        float h = bf2f(pu[j]) + bf2f(qu[j]) + bb[j];
        h = fmaxf(h, 0.f);
        acc = fmaf(h, ww[j], acc);
    }
    // reduce across the 16-lane group (masks < 16 stay in-group)
    acc += __shfl_xor(acc, 1);
    acc += __shfl_xor(acc, 2);
    acc += __shfl_xor(acc, 4);
    acc += __shfl_xor(acc, 8);

    if (sub == 0) out[e] = acc + b2[0];
}

// ---------------------------------------------------------------------------
extern "C" void kernel_launch(void* const* d_in, const int* in_sizes, int n_in,
                              void* d_out, int out_size, void* d_ws, size_t ws_size,
                              hipStream_t stream) {
    const float* z  = (const float*)d_in[0];
    const int*   ei = (const int*)d_in[1];
    const float* W1 = (const float*)d_in[2];
    const float* b1 = (const float*)d_in[3];
    const float* W2 = (const float*)d_in[4];
    const float* b2 = (const float*)d_in[5];
    float* out = (float*)d_out;

    const int M = in_sizes[0] / 128;   // 100000 nodes
    const int E = in_sizes[1] / 2;     // 640000 edges

    u16* Wl = (u16*)d_ws;                          // 64 KB
    u16* PQ = (u16*)((char*)d_ws + 65536);         // M*256*2 B = 51.2 MB

    hipLaunchKernelGGL(prep_w, dim3(128), dim3(256), 0, stream, W1, Wl);

    int gb = (M + BM - 1) / BM;
    hipLaunchKernelGGL(node_gemm, dim3(gb), dim3(256), 0, stream, z, Wl, PQ, M);

    int eb = (E * 16 + 255) / 256;
    hipLaunchKernelGGL(edge_mlp, dim3(eb), dim3(256), 0, stream,
                       ei, PQ, b1, W2, b2, out, E);
}